// Round 8
// baseline (2364.567 us; speedup 1.0000x reference)
//
#include <hip/hip_runtime.h>
#include <hip/hip_bf16.h>
#include <math.h>

typedef __hip_bfloat16 bf16;
typedef __attribute__((ext_vector_type(8))) short short8;
typedef __attribute__((ext_vector_type(4))) float f32x4;

#define HIDD   768
#define SEQL   197
#define NPATCH 196
#define PATCHD 256
#define NHEADS 12
#define NBATCH 8
#define OUTDIM 1000
#define NBLOCKS 6
#define EPSV   1e-5f
#define HH     (NHEADS * HIDD)       /* 9216 */
#define HH3    (3 * HH)              /* 27648 */
#define M_ALL  (NBATCH * SEQL)       /* 1576 */
#define SLD    224                   /* fp32 score row stride */
#define PLD    256                   /* bf16 prob row stride (zero-padded cols) */
#define KPV    224                   /* PV reduction length: 197 -> ceil32 */
#define KSPLIT 4

// ---------- helpers ----------
__device__ __forceinline__ unsigned short f2bf(float f) {
  union { bf16 h; unsigned short u; } cv; cv.h = __float2bfloat16(f); return cv.u;
}

typedef __attribute__((address_space(3))) unsigned int lds_uint;
typedef __attribute__((address_space(1))) const unsigned int g_uint;
__device__ __forceinline__ void gload16(const void* g, void* l) {
  // async global->LDS, 16 B per lane; LDS dest = wave-uniform base + lane*16
  __builtin_amdgcn_global_load_lds((g_uint*)g, (lds_uint*)l, 16, 0, 0);
}

// ---------- fp32 -> bf16 convert ----------
__global__ __launch_bounds__(256) void cvt_bf(const float4* __restrict__ src,
                                              ushort4* __restrict__ dst, int n4) {
  for (int i = blockIdx.x * 256 + threadIdx.x; i < n4; i += gridDim.x * 256) {
    float4 v = src[i];
    ushort4 o;
    o.x = f2bf(v.x); o.y = f2bf(v.y); o.z = f2bf(v.z); o.w = f2bf(v.w);
    dst[i] = o;
  }
}

// =================================================================
// gemm_bt: C = alpha * A @ B^T + bias.  A [M,K] bf16 (lda), B [N,K] bf16 (ldb).
// 256 threads = 4 waves in a WGM x WGN grid; wave tile (BM/WGM) x (BN/WGN).
// Wave tile 128x64 -> 42.7 FLOP per LDS byte (vs 32 at 64x64): LDS-BW-bound
// regime (R7 post-mortem: MfmaUtil == FLOPB * 85B/cyc / 13512 exactly).
// Triple-buffered global_load_lds pipeline, counted vmcnt, raw s_barrier.
// Bank-conflict swizzle (R7, verified 8.6M->0): LDS pos p of row r holds
// global chunk p ^ ((r>>1)&3) via permuted GLOBAL source; read with same XOR.
// K % 32 == 0. Edge tiles may read past M/N rows (caller keeps those
// addresses inside the workspace); stores are masked.
// =================================================================
template<int BM, int BN, int WGM, int WGN, bool BF16C>
__global__ __launch_bounds__(256, 2) void gemm_bt(
    const unsigned short* __restrict__ A, long long sAz1, long long sAz2, int lda,
    const unsigned short* __restrict__ B, long long sBz1, long long sBz2, int ldb,
    void* __restrict__ Cp, long long sCz1, long long sCz2, int ldc,
    const float* __restrict__ bias, int zdiv, float alpha,
    int M, int N, int K)
{
  constexpr int BK = 32;
  constexpr int VM = BM / 64 + BN / 64;     // gload instrs per stage, per wave
  static_assert(WGM * WGN == 4, "4 waves");
  __shared__ unsigned short As[3][BM * BK];
  __shared__ unsigned short Bs[3][BN * BK];

  const int z  = blockIdx.z;
  const int z1 = z / zdiv, z2 = z - z1 * zdiv;
  const unsigned short* Ab = A + z1 * sAz1 + z2 * sAz2;
  const unsigned short* Bb = B + z1 * sBz1 + z2 * sBz2;
  const long long coff = z1 * sCz1 + z2 * sCz2;

  const int tid = threadIdx.x;
  const int m0 = blockIdx.y * BM, n0 = blockIdx.x * BN;
  const int lane = tid & 63, wid = tid >> 6;
  const int wr = wid / WGN, wc = wid % WGN;
  constexpr int WM = BM / WGM, WN = BN / WGN, TM = WM / 16, TN = WN / 16;
  const int lr = lane & 15, g = lane >> 4;

  // staging geometry: per issue a wave covers 16 rows (4 lanes/row, 16 B each)
  const int sr = wid * 16 + (lane >> 2);     // row within the 64-row issue group
  // swizzled source chunk: LDS position (lane&3) receives global chunk
  // (lane&3) ^ ((row>>1)&3); (row>>1)&3 == (lane>>3)&3 for this geometry.
  const int sc = (((lane & 3) ^ ((lane >> 3) & 3)) * 8);
  const int wbyte = wid * 1024;              // wave's LDS byte base within an issue

  f32x4 acc[TM][TN];
#pragma unroll
  for (int m = 0; m < TM; ++m)
#pragma unroll
    for (int n = 0; n < TN; ++n) acc[m][n] = (f32x4){0.f, 0.f, 0.f, 0.f};

  auto stage = [&](int bufi, int kt) {
    const int k0 = kt * BK;
#pragma unroll
    for (int u = 0; u < BM / 64; ++u)
      gload16(Ab + (long long)(m0 + u * 64 + sr) * lda + k0 + sc,
              (char*)&As[bufi][0] + u * 4096 + wbyte);
#pragma unroll
    for (int u = 0; u < BN / 64; ++u)
      gload16(Bb + (long long)(n0 + u * 64 + sr) * ldb + k0 + sc,
              (char*)&Bs[bufi][0] + u * 4096 + wbyte);
  };

  // read-side swizzled chunk (in bf16 units): (g ^ ((lr>>1)&3)) * 8
  // valid for any row base multiple of 16 (WM, WN multiples of 16).
  const int rchunk = (g ^ ((lr >> 1) & 3)) * 8;

  const int ktiles = K / BK;
  stage(0, 0);
  if (ktiles > 1) stage(1, 1);
  int cur = 0;
  for (int t = 0; t < ktiles; ++t) {
    // wait: tile t landed. Steady state leaves tile t+1's VM loads in flight.
    if (t + 1 < ktiles) __builtin_amdgcn_s_waitcnt(0x0F70 | VM);
    else                __builtin_amdgcn_s_waitcnt(0x0F70);
    __builtin_amdgcn_s_barrier();
    if (t + 2 < ktiles) {
      int nb = cur + 2; if (nb >= 3) nb -= 3;
      stage(nb, t + 2);                      // issued post-barrier: old contents consumed
    }
    __builtin_amdgcn_sched_barrier(0);       // pin: no ds_read hoists above, no stage sinks

    short8 a[TM], b[TN];
#pragma unroll
    for (int m = 0; m < TM; ++m)
      a[m] = *(const short8*)&As[cur][(wr * WM + m * 16 + lr) * BK + rchunk];
#pragma unroll
    for (int n = 0; n < TN; ++n)
      b[n] = *(const short8*)&Bs[cur][(wc * WN + n * 16 + lr) * BK + rchunk];
#pragma unroll
    for (int m = 0; m < TM; ++m)
#pragma unroll
      for (int n = 0; n < TN; ++n)
        acc[m][n] = __builtin_amdgcn_mfma_f32_16x16x32_bf16(a[m], b[n], acc[m][n], 0, 0, 0);
    cur = (cur == 2) ? 0 : cur + 1;
  }

  // ---- epilogue: D col = lane&15, row = (lane>>4)*4 + r ----
#pragma unroll
  for (int m = 0; m < TM; ++m) {
#pragma unroll
    for (int n = 0; n < TN; ++n) {
      const int gn = n0 + wc * WN + n * 16 + lr;
      if (gn >= N) continue;
      const float bv = bias ? bias[gn] : 0.f;
#pragma unroll
      for (int r = 0; r < 4; ++r) {
        const int gm = m0 + wr * WM + m * 16 + g * 4 + r;
        if (gm >= M) continue;
        const float v = acc[m][n][r] * alpha + bv;
        if constexpr (BF16C)
          ((unsigned short*)Cp)[coff + (long long)gm * ldc + gn] = f2bf(v);
        else
          ((float*)Cp)[coff + (long long)gm * ldc + gn] = v;
      }
    }
  }
}

// =================================================================
// Reg-staged MFMA GEMM, kept for PV only (BT=false transpose staging).
// C = alpha * A @ B + bias; B is [K,N] (rows k >= Kvalid staged as zero).
// =================================================================
template<int BM, int BN, bool BF16C>
__global__ __launch_bounds__(256) void gemm_nn(
    const unsigned short* __restrict__ A, long long sAz1, long long sAz2, int lda,
    const unsigned short* __restrict__ Bb, long long sBz1, long long sBz2, int ldb,
    void* __restrict__ Cp, long long sCz1, long long sCz2, int ldc,
    const float* __restrict__ bias, int zdiv, float alpha,
    int M, int N, int K, int Kvalid)
{
  constexpr int BK = 32;
  constexpr int LP = 40;
  __shared__ unsigned short As[BM * LP];
  __shared__ unsigned short Bs[BN * LP];

  const int z  = blockIdx.z;
  const int z1 = z / zdiv, z2 = z - z1 * zdiv;
  const unsigned short* Ab = A + z1 * sAz1 + z2 * sAz2;
  const unsigned short* Bp = Bb + z1 * sBz1 + z2 * sBz2;
  const long long coff = z1 * sCz1 + z2 * sCz2;

  const int tid = threadIdx.x;
  const int m0 = blockIdx.y * BM, n0 = blockIdx.x * BN;
  const int lane = tid & 63, wid = tid >> 6;
  const int wr = wid >> 1, wc = wid & 1;
  constexpr int WM = BM / 2, WN = BN / 2, TM = WM / 16, TN = WN / 16;
  const int lr = lane & 15, g = lane >> 4;
  const int srow = tid >> 2, scg = tid & 3;

  f32x4 acc[TM][TN];
#pragma unroll
  for (int m = 0; m < TM; ++m)
#pragma unroll
    for (int n = 0; n < TN; ++n) acc[m][n] = (f32x4){0.f, 0.f, 0.f, 0.f};

  for (int k0 = 0; k0 < K; k0 += BK) {
#pragma unroll
    for (int u = 0; u < BM / 64; ++u) {
      const int row = u * 64 + srow;
      const int gm = m0 + row;
      int4 val = {0, 0, 0, 0};
      if (gm < M)
        val = *(const int4*)(Ab + (long long)gm * lda + k0 + scg * 8);
      *(int4*)&As[row * LP + scg * 8] = val;
    }
    {
      constexpr int CH = BN / 8;
      constexpr int KP = BK / 2;
      static_assert(KP * CH <= 256, "staging exceeds block");
      if (tid < KP * CH) {
        const int kp = tid / CH;
        const int c8 = (tid - kp * CH) * 8;
        const int gn = n0 + c8;
        const int gk0 = k0 + 2 * kp;
        unsigned short r0[8] = {0,0,0,0,0,0,0,0};
        unsigned short r1[8] = {0,0,0,0,0,0,0,0};
        if (gk0 < Kvalid) {
          if (gn + 7 < N) *(int4*)r0 = *(const int4*)(Bp + (long long)gk0 * ldb + gn);
          else { for (int j = 0; j < 8; ++j) if (gn + j < N) r0[j] = Bp[(long long)gk0 * ldb + gn + j]; }
        }
        if (gk0 + 1 < Kvalid) {
          if (gn + 7 < N) *(int4*)r1 = *(const int4*)(Bp + (long long)(gk0 + 1) * ldb + gn);
          else { for (int j = 0; j < 8; ++j) if (gn + j < N) r1[j] = Bp[(long long)(gk0 + 1) * ldb + gn + j]; }
        }
#pragma unroll
        for (int j = 0; j < 8; ++j)
          *(unsigned int*)&Bs[(c8 + j) * LP + 2 * kp] =
              (unsigned int)r0[j] | ((unsigned int)r1[j] << 16);
      }
    }
    __syncthreads();

    short8 a[TM], b[TN];
#pragma unroll
    for (int m = 0; m < TM; ++m)
      a[m] = *(const short8*)&As[(wr * WM + m * 16 + lr) * LP + g * 8];
#pragma unroll
    for (int n = 0; n < TN; ++n)
      b[n] = *(const short8*)&Bs[(wc * WN + n * 16 + lr) * LP + g * 8];
#pragma unroll
    for (int m = 0; m < TM; ++m)
#pragma unroll
      for (int n = 0; n < TN; ++n)
        acc[m][n] = __builtin_amdgcn_mfma_f32_16x16x32_bf16(a[m], b[n], acc[m][n], 0, 0, 0);
    __syncthreads();
  }

#pragma unroll
  for (int m = 0; m < TM; ++m) {
#pragma unroll
    for (int n = 0; n < TN; ++n) {
      const int gn = n0 + wc * WN + n * 16 + lr;
      if (gn >= N) continue;
      const float bv = bias ? bias[gn] : 0.f;
#pragma unroll
      for (int r = 0; r < 4; ++r) {
        const int gm = m0 + wr * WM + m * 16 + g * 4 + r;
        if (gm >= M) continue;
        const float v = acc[m][n][r] * alpha + bv;
        if constexpr (BF16C)
          ((unsigned short*)Cp)[coff + (long long)gm * ldc + gn] = f2bf(v);
        else
          ((float*)Cp)[coff + (long long)gm * ldc + gn] = v;
      }
    }
  }
}

// =================================================================
// fp32 vector-ALU GEMM (tiny patch-embed and head)
// =================================================================
template<int BM, int BN>
__global__ __launch_bounds__(256) void gemm_k(
    const float* __restrict__ A, long long sAz1, int lda,
    const float* __restrict__ B, int ldb,
    float* __restrict__ C, long long sCz1, int ldc,
    const float* __restrict__ bias,
    const float* __restrict__ resid, int ldr,
    float alpha, int M, int N, int K, int act)
{
  constexpr int BK = 16;
  constexpr int TM = BM / 16;
  constexpr int TN = BN / 16;
  __shared__ float As[BK][BM];
  __shared__ float Bs[BK][BN];

  const int z = blockIdx.z;
  A += z * sAz1;
  C += z * sCz1;
  const float* R = resid;

  const int tid = threadIdx.x;
  const int tx = tid & 15, ty = tid >> 4;
  const int m0 = blockIdx.y * BM, n0 = blockIdx.x * BN;

  float acc[TM][TN];
#pragma unroll
  for (int i = 0; i < TM; ++i)
#pragma unroll
    for (int j = 0; j < TN; ++j) acc[i][j] = 0.f;

  for (int k0 = 0; k0 < K; k0 += BK) {
    {
      constexpr int AV = (BM * BK / 4) / 256;
#pragma unroll
      for (int u = 0; u < AV; ++u) {
        const int vi = tid + u * 256;
        const int r  = vi / (BK / 4);
        const int c4 = (vi % (BK / 4)) * 4;
        const int gm = m0 + r, gk = k0 + c4;
        float4 v = {0.f, 0.f, 0.f, 0.f};
        if (gm < M) v = *(const float4*)(A + (long long)gm * lda + gk);
        As[c4 + 0][r] = v.x; As[c4 + 1][r] = v.y;
        As[c4 + 2][r] = v.z; As[c4 + 3][r] = v.w;
      }
    }
    {
      constexpr int BV = (BN * BK / 4) / 256;
#pragma unroll
      for (int u = 0; u < BV; ++u) {
        const int vi = tid + u * 256;
        const int r  = vi / (BK / 4);
        const int c4 = (vi % (BK / 4)) * 4;
        const int gn = n0 + r, gk = k0 + c4;
        float4 v = {0.f, 0.f, 0.f, 0.f};
        if (gn < N) v = *(const float4*)(B + (long long)gn * ldb + gk);
        Bs[c4 + 0][r] = v.x; Bs[c4 + 1][r] = v.y;
        Bs[c4 + 2][r] = v.z; Bs[c4 + 3][r] = v.w;
      }
    }
    __syncthreads();
#pragma unroll
    for (int kk = 0; kk < BK; ++kk) {
      float a[TM], bb[TN];
#pragma unroll
      for (int i = 0; i < TM; i += 4)
        *reinterpret_cast<float4*>(&a[i]) = *reinterpret_cast<const float4*>(&As[kk][ty * TM + i]);
#pragma unroll
      for (int j = 0; j < TN; j += 4)
        *reinterpret_cast<float4*>(&bb[j]) = *reinterpret_cast<const float4*>(&Bs[kk][tx * TN + j]);
#pragma unroll
      for (int i = 0; i < TM; ++i)
#pragma unroll
        for (int j = 0; j < TN; ++j) acc[i][j] = fmaf(a[i], bb[j], acc[i][j]);
    }
    __syncthreads();
  }

#pragma unroll
  for (int i = 0; i < TM; ++i) {
    const int gm = m0 + ty * TM + i;
    if (gm >= M) continue;
#pragma unroll
    for (int j = 0; j < TN; ++j) {
      const int gn = n0 + tx * TN + j;
      if (gn >= N) continue;
      float v = acc[i][j] * alpha;
      if (bias) v += bias[gn];
      if (R)    v += R[(long long)gm * ldr + gn];
      if (act)  v = tanhf(v);
      C[(long long)gm * ldc + gn] = v;
    }
  }
}

// ---------- LayerNorm over whole (SEQ,HID) per sample ----------
__global__ __launch_bounds__(256) void ln_part(const float* __restrict__ x, float* __restrict__ part) {
  const int b = blockIdx.x;            // 0..127
  const int n = b >> 4, seg = b & 15;
  const int per = (SEQL * HIDD / 4) / 16;
  const float4* px = (const float4*)(x + (size_t)n * SEQL * HIDD);
  float s = 0.f, q = 0.f;
  for (int i = seg * per + threadIdx.x; i < (seg + 1) * per; i += 256) {
    float4 v = px[i];
    s += v.x + v.y + v.z + v.w;
    q += v.x * v.x + v.y * v.y + v.z * v.z + v.w * v.w;
  }
  for (int o = 32; o; o >>= 1) { s += __shfl_xor(s, o, 64); q += __shfl_xor(q, o, 64); }
  __shared__ float ls[8];
  const int wid = threadIdx.x >> 6, lane = threadIdx.x & 63;
  if (lane == 0) { ls[wid] = s; ls[4 + wid] = q; }
  __syncthreads();
  if (threadIdx.x == 0) {
    part[b] = ls[0] + ls[1] + ls[2] + ls[3];
    part[128 + b] = ls[4] + ls[5] + ls[6] + ls[7];
  }
}

__global__ void ln_fin(float* __restrict__ stats) {
  const int n = blockIdx.x; const int lane = threadIdx.x;  // 64 threads
  float s = (lane < 16) ? stats[n * 16 + lane] : 0.f;
  float q = (lane < 16) ? stats[128 + n * 16 + lane] : 0.f;
  for (int o = 8; o; o >>= 1) { s += __shfl_xor(s, o, 64); q += __shfl_xor(q, o, 64); }
  if (lane == 0) {
    const float inv = 1.f / (float)(SEQL * HIDD);
    const float m = s * inv;
    const float var = q * inv - m * m;
    stats[256 + 2 * n] = m;
    stats[257 + 2 * n] = rsqrtf(var + EPSV);
  }
}

// LN apply -> bf16
__global__ __launch_bounds__(256) void ln_apply_bf(const float* __restrict__ x,
    const float* __restrict__ g, const float* __restrict__ b,
    const float* __restrict__ st, unsigned short* __restrict__ y)
{
  const int tot = NBATCH * SEQL * HIDD / 4;
  for (int i = blockIdx.x * 256 + threadIdx.x; i < tot; i += gridDim.x * 256) {
    const int n  = i / (SEQL * HIDD / 4);
    const int se = i - n * (SEQL * HIDD / 4);
    const float m = st[2 * n], r = st[2 * n + 1];
    float4 xv = ((const float4*)x)[i];
    float4 gv = ((const float4*)g)[se];
    float4 bv = ((const float4*)b)[se];
    ushort4 o;
    o.x = f2bf((xv.x - m) * r * gv.x + bv.x);
    o.y = f2bf((xv.y - m) * r * gv.y + bv.y);
    o.z = f2bf((xv.z - m) * r * gv.z + bv.z);
    o.w = f2bf((xv.w - m) * r * gv.w + bv.w);
    ((ushort4*)y)[i] = o;
  }
}

// ---------- softmax fp32 (ld 224) -> bf16 (ld 256, zero-padded) ----------
__global__ __launch_bounds__(256) void softmax_bf(const float* __restrict__ S,
                                                  unsigned short* __restrict__ P, int nrows) {
  const int row = blockIdx.x * 4 + (threadIdx.x >> 6);
  const int lane = threadIdx.x & 63;
  if (row >= nrows) return;
  const float* p = S + (long long)row * SLD;
  float v[4];
  float mx = -1e30f;
#pragma unroll
  for (int j = 0; j < 4; ++j) {
    const int t = lane + 64 * j;
    v[j] = (t < SEQL) ? p[t] : -1e30f;
    mx = fmaxf(mx, v[j]);
  }
  for (int o = 32; o; o >>= 1) mx = fmaxf(mx, __shfl_xor(mx, o, 64));
  float sum = 0.f;
#pragma unroll
  for (int j = 0; j < 4; ++j) {
    const int t = lane + 64 * j;
    v[j] = (t < SEQL) ? __expf(v[j] - mx) : 0.f;
    sum += v[j];
  }
  for (int o = 32; o; o >>= 1) sum += __shfl_xor(sum, o, 64);
  const float inv = 1.f / sum;
  unsigned short* q = P + (long long)row * PLD;
#pragma unroll
  for (int j = 0; j < 4; ++j) {
    const int t = lane + 64 * j;
    q[t] = f2bf(v[j] * inv);
  }
}

// ---------- Wo split-K reduce: Ares = sum_s Cpart[s] + bo + Z ----------
__global__ __launch_bounds__(256) void wo_reduce(const float4* __restrict__ Cp,
    const float4* __restrict__ Z4, const float4* __restrict__ bo4,
    float4* __restrict__ out4)
{
  const int tot = M_ALL * HIDD / 4;
  for (int i = blockIdx.x * 256 + threadIdx.x; i < tot; i += gridDim.x * 256) {
    float4 a = Cp[i], b = Cp[tot + i], c = Cp[2 * tot + i], d = Cp[3 * tot + i];
    float4 z = Z4[i];
    float4 bb = bo4[i % (HIDD / 4)];
    float4 o;
    o.x = a.x + b.x + c.x + d.x + z.x + bb.x;
    o.y = a.y + b.y + c.y + d.y + z.y + bb.y;
    o.z = a.z + b.z + c.z + d.z + z.z + bb.z;
    o.w = a.w + b.w + c.w + d.w + z.w + bb.w;
    out4[i] = o;
  }
}

// ---------- CLS row init ----------
__global__ void cls_pos(const float* __restrict__ cls, const float* __restrict__ pos,
                        float* __restrict__ Z) {
  const int n = blockIdx.x;
  for (int e = threadIdx.x; e < HIDD; e += 256)
    Z[(size_t)n * SEQL * HIDD + e] = cls[e] + pos[e];
}

// ---------------------------------------------------------------
extern "C" void kernel_launch(void* const* d_in, const int* in_sizes, int n_in,
                              void* d_out, int out_size, void* d_ws, size_t ws_size,
                              hipStream_t stream)
{
  const float* X    = (const float*)d_in[0];
  const float* Wp   = (const float*)d_in[1];
  const float* bp   = (const float*)d_in[2];
  const float* cls  = (const float*)d_in[3];
  const float* pos  = (const float*)d_in[4];
  const float* ln1g = (const float*)d_in[5];
  const float* ln1b = (const float*)d_in[6];
  const float* Wq   = (const float*)d_in[7];
  const float* bq   = (const float*)d_in[8];
  const float* Wk   = (const float*)d_in[9];
  const float* bk   = (const float*)d_in[10];
  const float* Wv   = (const float*)d_in[11];
  const float* bv   = (const float*)d_in[12];
  const float* Wo   = (const float*)d_in[13];
  const float* bo   = (const float*)d_in[14];
  const float* ln2g = (const float*)d_in[15];
  const float* ln2b = (const float*)d_in[16];
  const float* W2   = (const float*)d_in[17];
  const float* b2   = (const float*)d_in[18];
  const float* Wh   = (const float*)d_in[19];
  const float* bh   = (const float*)d_in[20];
  float* out = (float*)d_out;
  (void)in_sizes; (void)n_in; (void)out_size; (void)ws_size;

  // NOTE: allocation ORDER matters — gemm_bt edge tiles read up to ~12 MB past
  // QKVb/Xnb ends; the weight copies placed after them keep those reads mapped.
  char* base = (char*)d_ws;
  size_t off = 0;
  auto alloc = [&](size_t bytes) -> char* {
    char* r = base + off;
    off += (bytes + 255) & ~(size_t)255;
    return r;
  };
  const size_t ZB   = (size_t)M_ALL * HIDD * 4;
  const size_t XB   = (size_t)M_ALL * HIDD * 2;
  const size_t SFB  = (size_t)NBATCH * NHEADS * SEQL * SLD * 4;
  const size_t PB   = (size_t)NBATCH * NHEADS * SEQL * PLD * 2;
  const size_t QKVB = (size_t)M_ALL * HH3 * 2;               // 87.15 MB
  const size_t WQB  = (size_t)HH3 * HIDD * 2;                // 42.47 MB
  const size_t WOB  = (size_t)HH * HIDD * 2;                 // 14.16 MB
  const size_t W2B  = (size_t)HIDD * HIDD * 2;

  float*          Z     = (float*)alloc(ZB);
  float*          Ares  = (float*)alloc(ZB);
  unsigned short* Xnb   = (unsigned short*)alloc(XB);
  float*          stats = (float*)alloc(4096);
  float*          Sf    = (float*)alloc(SFB);
  unsigned short* Pb    = (unsigned short*)alloc(PB);
  unsigned short* QKVb  = (unsigned short*)alloc(QKVB);   // Q|K|V slices; H overwrites Q
  unsigned short* Wqkv_bf = (unsigned short*)alloc(WQB);
  unsigned short* Wo_bf   = (unsigned short*)alloc(WOB);
  unsigned short* W2_bf   = (unsigned short*)alloc(W2B);
  float*          bqkv    = (float*)alloc(HH3 * 4);
  float*          Cpart   = (float*)Sf;   // Wo split-K partials alias Sf

  const float scale = 1.0f / ((float)HIDD * (float)HIDD);
  const long long sTn = (long long)SEQL * HH3;
  const long long sSn = (long long)NHEADS * SEQL * SLD;
  const long long sSh = (long long)SEQL * SLD;
  const long long sPn = (long long)NHEADS * SEQL * PLD;
  const long long sPh = (long long)SEQL * PLD;
  const int WO4 = HH * HIDD / 4, W24 = HIDD * HIDD / 4;

  // ---- one-time weight conversion ----
  cvt_bf<<<dim3(4096), 256, 0, stream>>>((const float4*)Wq, (ushort4*)(Wqkv_bf), WO4);
  cvt_bf<<<dim3(4096), 256, 0, stream>>>((const float4*)Wk, (ushort4*)(Wqkv_bf + (size_t)HH * HIDD), WO4);
  cvt_bf<<<dim3(4096), 256, 0, stream>>>((const float4*)Wv, (ushort4*)(Wqkv_bf + (size_t)2 * HH * HIDD), WO4);
  cvt_bf<<<dim3(4096), 256, 0, stream>>>((const float4*)Wo, (ushort4*)Wo_bf, WO4);
  cvt_bf<<<dim3(512),  256, 0, stream>>>((const float4*)W2, (ushort4*)W2_bf, W24);
  hipMemcpyAsync(bqkv,          bq, (size_t)HH * 4, hipMemcpyDeviceToDevice, stream);
  hipMemcpyAsync(bqkv + HH,     bk, (size_t)HH * 4, hipMemcpyDeviceToDevice, stream);
  hipMemcpyAsync(bqkv + 2 * HH, bv, (size_t)HH * 4, hipMemcpyDeviceToDevice, stream);

  // ---- embed ----
  cls_pos<<<dim3(NBATCH), 256, 0, stream>>>(cls, pos, Z);
  gemm_k<64, 64><<<dim3(HIDD / 64, (NPATCH + 63) / 64, NBATCH), 256, 0, stream>>>(
      X, (long long)NPATCH * PATCHD, PATCHD,
      Wp, PATCHD,
      Z + HIDD, (long long)SEQL * HIDD, HIDD,
      bp, pos + HIDD, HIDD,
      1.0f, NPATCH, HIDD, PATCHD, 0);

  for (int blk = 0; blk < NBLOCKS; ++blk) {
    // ---- LN1 -> Xnb (bf16) ----
    ln_part<<<dim3(128), 256, 0, stream>>>(Z, stats);
    ln_fin<<<dim3(NBATCH), 64, 0, stream>>>(stats);
    ln_apply_bf<<<dim3(1182), 256, 0, stream>>>(Z, ln1g, ln1b, stats + 256, Xnb);

    // ---- fused QKV: [1576,768] @ [27648,768]^T -> bf16 [1576,27648] ----
    gemm_bt<256, 128, 2, 2, true><<<dim3(HH3 / 128, 7, 1), 256, 0, stream>>>(
        Xnb, 0, 0, HIDD, Wqkv_bf, 0, 0, HIDD, QKVb, 0, 0, HH3,
        bqkv, 1, 1.0f, M_ALL, HH3, HIDD);

    // ---- scores: Sf[z] = scale * Q[z] @ K[z]^T  (z = n*12+h) ----
    gemm_bt<128, 128, 2, 2, false><<<dim3(2, 2, NBATCH * NHEADS), 256, 0, stream>>>(
        QKVb, sTn, HIDD, HH3,
        QKVb + HH, sTn, HIDD, HH3,
        Sf, sSn, sSh, SLD,
        nullptr, NHEADS, scale, SEQL, SEQL, HIDD);

    // ---- softmax rows -> Pb ----
    softmax_bf<<<dim3(NBATCH * NHEADS * SEQL / 4), 256, 0, stream>>>(
        Sf, Pb, NBATCH * NHEADS * SEQL);

    // ---- PV: H[z] = P[z] @ V[z]; H into the dead Q column slice ----
    gemm_nn<64, 128, true><<<dim3(HIDD / 128, 4, NBATCH * NHEADS), 256, 0, stream>>>(
        Pb, sPn, sPh, PLD,
        QKVb + 2 * HH, sTn, HIDD, HH3,
        QKVb, sTn, HIDD, HH3,
        nullptr, NHEADS, 1.0f, SEQL, HIDD, KPV, SEQL);

    // ---- Wo split-K: Cpart[s] = H[:, s*2304:(s+1)*2304] @ Wo_s^T ----
    gemm_bt<256, 128, 2, 2, false><<<dim3(HIDD / 128, 7, KSPLIT), 256, 0, stream>>>(
        QKVb, 0, HH / KSPLIT, HH3,
        Wo_bf, 0, HH / KSPLIT, HH,
        Cpart, 0, (long long)M_ALL * HIDD, HIDD,
        nullptr, KSPLIT, 1.0f, M_ALL, HIDD, HH / KSPLIT);

    // ---- reduce + bias + residual -> Ares ----
    wo_reduce<<<dim3(1182), 256, 0, stream>>>(
        (const float4*)Cpart, (const float4*)Z, (const float4*)bo, (float4*)Ares);

    // ---- LN2 -> Xnb (bf16) ----
    ln_part<<<dim3(128), 256, 0, stream>>>(Ares, stats);
    ln_fin<<<dim3(NBATCH), 64, 0, stream>>>(stats);
    ln_apply_bf<<<dim3(1182), 256, 0, stream>>>(Ares, ln2g, ln2b, stats + 256, Xnb);

    // ---- W2: Z = Xnb @ W2^T + b2 (fp32 out) ----
    gemm_bt<256, 128, 2, 2, false><<<dim3(HIDD / 128, 7, 1), 256, 0, stream>>>(
        Xnb, 0, 0, HIDD, W2_bf, 0, 0, HIDD, Z, 0, 0, HIDD,
        b2, 1, 1.0f, M_ALL, HIDD, HIDD);
  }

  // ---- head: out = tanh(Z[:,0,:] @ Wh^T + bh) ----
  gemm_k<64, 64><<<dim3((OUTDIM + 63) / 64, 1, 1), 256, 0, stream>>>(
      Z, 0, SEQL * HIDD,
      Wh, HIDD,
      out, 0, OUTDIM,
      bh, nullptr, 0,
      1.0f, NBATCH, OUTDIM, HIDD, 1);
}

// Round 9
// 2018.454 us; speedup vs baseline: 1.1715x; 1.1715x over previous
//
#include <hip/hip_runtime.h>
#include <hip/hip_bf16.h>
#include <math.h>

typedef __hip_bfloat16 bf16;
typedef __attribute__((ext_vector_type(8))) short short8;
typedef __attribute__((ext_vector_type(4))) float f32x4;

#define HIDD   768
#define SEQL   197
#define NPATCH 196
#define PATCHD 256
#define NHEADS 12
#define NBATCH 8
#define OUTDIM 1000
#define NBLOCKS 6
#define EPSV   1e-5f
#define HH     (NHEADS * HIDD)       /* 9216 */
#define HH3    (3 * HH)              /* 27648 */
#define M_ALL  (NBATCH * SEQL)       /* 1576 */
#define SLD    224                   /* fp32 score row stride */
#define PLD    256                   /* bf16 prob row stride (zero-padded cols) */
#define KPV    224                   /* PV reduction length: 197 -> ceil32 */
#define KSPLIT 4

// ---------- helpers ----------
__device__ __forceinline__ unsigned short f2bf(float f) {
  union { bf16 h; unsigned short u; } cv; cv.h = __float2bfloat16(f); return cv.u;
}

typedef __attribute__((address_space(3))) unsigned int lds_uint;
typedef __attribute__((address_space(1))) const unsigned int g_uint;
__device__ __forceinline__ void gload16(const void* g, void* l) {
  // async global->LDS, 16 B per lane; LDS dest = wave-uniform base + lane*16
  __builtin_amdgcn_global_load_lds((g_uint*)g, (lds_uint*)l, 16, 0, 0);
}

// ---------- fp32 -> bf16 convert ----------
__global__ __launch_bounds__(256) void cvt_bf(const float4* __restrict__ src,
                                              ushort4* __restrict__ dst, int n4) {
  for (int i = blockIdx.x * 256 + threadIdx.x; i < n4; i += gridDim.x * 256) {
    float4 v = src[i];
    ushort4 o;
    o.x = f2bf(v.x); o.y = f2bf(v.y); o.z = f2bf(v.z); o.w = f2bf(v.w);
    dst[i] = o;
  }
}

// =================================================================
// gemm_bt: C = alpha * A @ B^T + bias.  A [M,K] bf16 (lda), B [N,K] bf16 (ldb).
// 4 waves in WGM x WGN grid; grid.x = (N/BN)*gy flattened (gy = m-tiles).
// XCD-bijective remap (m204): XCD k gets a CONTIGUOUS f-range; decompose
// f with m fastest -> each XCD keeps one B-tile L2-hot for gy blocks.
// Triple-buffered global_load_lds pipeline, counted vmcnt, raw s_barrier.
// Bank-conflict swizzle (R7, verified 8.6M->0): LDS pos p of row r holds
// global chunk p ^ ((r>>1)&3) via permuted GLOBAL source; read same XOR.
// K % 32 == 0. Edge tiles may read past M/N rows (caller keeps those
// addresses inside the workspace); stores are masked.
// =================================================================
template<int BM, int BN, int WGM, int WGN, bool BF16C>
__global__ __launch_bounds__(256, 2) void gemm_bt(
    const unsigned short* __restrict__ A, long long sAz1, long long sAz2, int lda,
    const unsigned short* __restrict__ B, long long sBz1, long long sBz2, int ldb,
    void* __restrict__ Cp, long long sCz1, long long sCz2, int ldc,
    const float* __restrict__ bias, int zdiv, float alpha,
    int M, int N, int K, int gy)
{
  constexpr int BK = 32;
  constexpr int VM = BM / 64 + BN / 64;     // gload instrs per stage, per wave
  static_assert(WGM * WGN == 4, "4 waves");
  __shared__ unsigned short As[3][BM * BK];
  __shared__ unsigned short Bs[3][BN * BK];

  const int z  = blockIdx.z;
  const int z1 = z / zdiv, z2 = z - z1 * zdiv;
  const unsigned short* Ab = A + z1 * sAz1 + z2 * sAz2;
  const unsigned short* Bb = B + z1 * sBz1 + z2 * sBz2;
  const long long coff = z1 * sCz1 + z2 * sCz2;

  // ---- XCD-bijective remap (m204), m-fastest within an XCD's f-range ----
  const int nwg = gridDim.x;
  const int qq = nwg >> 3, rr = nwg & 7;
  const int xcd = blockIdx.x & 7, wix = blockIdx.x >> 3;
  const int f = xcd * qq + (xcd < rr ? xcd : rr) + wix;
  const int m0 = (f % gy) * BM, n0 = (f / gy) * BN;

  const int tid = threadIdx.x;
  const int lane = tid & 63, wid = tid >> 6;
  const int wr = wid / WGN, wc = wid % WGN;
  constexpr int WM = BM / WGM, WN = BN / WGN, TM = WM / 16, TN = WN / 16;
  const int lr = lane & 15, g = lane >> 4;

  // staging geometry: per issue a wave covers 16 rows (4 lanes/row, 16 B each)
  const int sr = wid * 16 + (lane >> 2);     // row within the 64-row issue group
  // swizzled source chunk: LDS position (lane&3) receives global chunk
  // (lane&3) ^ ((row>>1)&3); (row>>1)&3 == (lane>>3)&3 for this geometry.
  const int sc = (((lane & 3) ^ ((lane >> 3) & 3)) * 8);
  const int wbyte = wid * 1024;              // wave's LDS byte base within an issue

  f32x4 acc[TM][TN];
#pragma unroll
  for (int m = 0; m < TM; ++m)
#pragma unroll
    for (int n = 0; n < TN; ++n) acc[m][n] = (f32x4){0.f, 0.f, 0.f, 0.f};

  auto stage = [&](int bufi, int kt) {
    const int k0 = kt * BK;
#pragma unroll
    for (int u = 0; u < BM / 64; ++u)
      gload16(Ab + (long long)(m0 + u * 64 + sr) * lda + k0 + sc,
              (char*)&As[bufi][0] + u * 4096 + wbyte);
#pragma unroll
    for (int u = 0; u < BN / 64; ++u)
      gload16(Bb + (long long)(n0 + u * 64 + sr) * ldb + k0 + sc,
              (char*)&Bs[bufi][0] + u * 4096 + wbyte);
  };

  // read-side swizzled chunk (in bf16 units): (g ^ ((lr>>1)&3)) * 8
  const int rchunk = (g ^ ((lr >> 1) & 3)) * 8;

  const int ktiles = K / BK;
  stage(0, 0);
  if (ktiles > 1) stage(1, 1);
  int cur = 0;
  for (int t = 0; t < ktiles; ++t) {
    // wait: tile t landed. Steady state leaves tile t+1's VM loads in flight.
    if (t + 1 < ktiles) __builtin_amdgcn_s_waitcnt(0x0F70 | VM);
    else                __builtin_amdgcn_s_waitcnt(0x0F70);
    __builtin_amdgcn_s_barrier();
    if (t + 2 < ktiles) {
      int nb = cur + 2; if (nb >= 3) nb -= 3;
      stage(nb, t + 2);                      // issued post-barrier: old contents consumed
    }
    __builtin_amdgcn_sched_barrier(0);       // pin: no ds_read hoists above, no stage sinks

    short8 a[TM], b[TN];
#pragma unroll
    for (int m = 0; m < TM; ++m)
      a[m] = *(const short8*)&As[cur][(wr * WM + m * 16 + lr) * BK + rchunk];
#pragma unroll
    for (int n = 0; n < TN; ++n)
      b[n] = *(const short8*)&Bs[cur][(wc * WN + n * 16 + lr) * BK + rchunk];
#pragma unroll
    for (int m = 0; m < TM; ++m)
#pragma unroll
      for (int n = 0; n < TN; ++n)
        acc[m][n] = __builtin_amdgcn_mfma_f32_16x16x32_bf16(a[m], b[n], acc[m][n], 0, 0, 0);
    cur = (cur == 2) ? 0 : cur + 1;
  }

  // ---- epilogue: D col = lane&15, row = (lane>>4)*4 + r ----
#pragma unroll
  for (int m = 0; m < TM; ++m) {
#pragma unroll
    for (int n = 0; n < TN; ++n) {
      const int gn = n0 + wc * WN + n * 16 + lr;
      if (gn >= N) continue;
      const float bv = bias ? bias[gn] : 0.f;
#pragma unroll
      for (int r = 0; r < 4; ++r) {
        const int gm = m0 + wr * WM + m * 16 + g * 4 + r;
        if (gm >= M) continue;
        const float v = acc[m][n][r] * alpha + bv;
        if constexpr (BF16C)
          ((unsigned short*)Cp)[coff + (long long)gm * ldc + gn] = f2bf(v);
        else
          ((float*)Cp)[coff + (long long)gm * ldc + gn] = v;
      }
    }
  }
}

// =================================================================
// Reg-staged MFMA GEMM, kept for PV only (BT=false transpose staging).
// C = alpha * A @ B + bias; B is [K,N] (rows k >= Kvalid staged as zero).
// =================================================================
template<int BM, int BN, bool BF16C>
__global__ __launch_bounds__(256) void gemm_nn(
    const unsigned short* __restrict__ A, long long sAz1, long long sAz2, int lda,
    const unsigned short* __restrict__ Bb, long long sBz1, long long sBz2, int ldb,
    void* __restrict__ Cp, long long sCz1, long long sCz2, int ldc,
    const float* __restrict__ bias, int zdiv, float alpha,
    int M, int N, int K, int Kvalid)
{
  constexpr int BK = 32;
  constexpr int LP = 40;
  __shared__ unsigned short As[BM * LP];
  __shared__ unsigned short Bs[BN * LP];

  const int z  = blockIdx.z;
  const int z1 = z / zdiv, z2 = z - z1 * zdiv;
  const unsigned short* Ab = A + z1 * sAz1 + z2 * sAz2;
  const unsigned short* Bp = Bb + z1 * sBz1 + z2 * sBz2;
  const long long coff = z1 * sCz1 + z2 * sCz2;

  const int tid = threadIdx.x;
  const int m0 = blockIdx.y * BM, n0 = blockIdx.x * BN;
  const int lane = tid & 63, wid = tid >> 6;
  const int wr = wid >> 1, wc = wid & 1;
  constexpr int WM = BM / 2, WN = BN / 2, TM = WM / 16, TN = WN / 16;
  const int lr = lane & 15, g = lane >> 4;
  const int srow = tid >> 2, scg = tid & 3;

  f32x4 acc[TM][TN];
#pragma unroll
  for (int m = 0; m < TM; ++m)
#pragma unroll
    for (int n = 0; n < TN; ++n) acc[m][n] = (f32x4){0.f, 0.f, 0.f, 0.f};

  for (int k0 = 0; k0 < K; k0 += BK) {
#pragma unroll
    for (int u = 0; u < BM / 64; ++u) {
      const int row = u * 64 + srow;
      const int gm = m0 + row;
      int4 val = {0, 0, 0, 0};
      if (gm < M)
        val = *(const int4*)(Ab + (long long)gm * lda + k0 + scg * 8);
      *(int4*)&As[row * LP + scg * 8] = val;
    }
    {
      constexpr int CH = BN / 8;
      constexpr int KP = BK / 2;
      static_assert(KP * CH <= 256, "staging exceeds block");
      if (tid < KP * CH) {
        const int kp = tid / CH;
        const int c8 = (tid - kp * CH) * 8;
        const int gn = n0 + c8;
        const int gk0 = k0 + 2 * kp;
        unsigned short r0[8] = {0,0,0,0,0,0,0,0};
        unsigned short r1[8] = {0,0,0,0,0,0,0,0};
        if (gk0 < Kvalid) {
          if (gn + 7 < N) *(int4*)r0 = *(const int4*)(Bp + (long long)gk0 * ldb + gn);
          else { for (int j = 0; j < 8; ++j) if (gn + j < N) r0[j] = Bp[(long long)gk0 * ldb + gn + j]; }
        }
        if (gk0 + 1 < Kvalid) {
          if (gn + 7 < N) *(int4*)r1 = *(const int4*)(Bp + (long long)(gk0 + 1) * ldb + gn);
          else { for (int j = 0; j < 8; ++j) if (gn + j < N) r1[j] = Bp[(long long)(gk0 + 1) * ldb + gn + j]; }
        }
#pragma unroll
        for (int j = 0; j < 8; ++j)
          *(unsigned int*)&Bs[(c8 + j) * LP + 2 * kp] =
              (unsigned int)r0[j] | ((unsigned int)r1[j] << 16);
      }
    }
    __syncthreads();

    short8 a[TM], b[TN];
#pragma unroll
    for (int m = 0; m < TM; ++m)
      a[m] = *(const short8*)&As[(wr * WM + m * 16 + lr) * LP + g * 8];
#pragma unroll
    for (int n = 0; n < TN; ++n)
      b[n] = *(const short8*)&Bs[(wc * WN + n * 16 + lr) * LP + g * 8];
#pragma unroll
    for (int m = 0; m < TM; ++m)
#pragma unroll
      for (int n = 0; n < TN; ++n)
        acc[m][n] = __builtin_amdgcn_mfma_f32_16x16x32_bf16(a[m], b[n], acc[m][n], 0, 0, 0);
    __syncthreads();
  }

#pragma unroll
  for (int m = 0; m < TM; ++m) {
#pragma unroll
    for (int n = 0; n < TN; ++n) {
      const int gn = n0 + wc * WN + n * 16 + lr;
      if (gn >= N) continue;
      const float bv = bias ? bias[gn] : 0.f;
#pragma unroll
      for (int r = 0; r < 4; ++r) {
        const int gm = m0 + wr * WM + m * 16 + g * 4 + r;
        if (gm >= M) continue;
        const float v = acc[m][n][r] * alpha + bv;
        if constexpr (BF16C)
          ((unsigned short*)Cp)[coff + (long long)gm * ldc + gn] = f2bf(v);
        else
          ((float*)Cp)[coff + (long long)gm * ldc + gn] = v;
      }
    }
  }
}

// =================================================================
// fp32 vector-ALU GEMM (tiny patch-embed and head)
// =================================================================
template<int BM, int BN>
__global__ __launch_bounds__(256) void gemm_k(
    const float* __restrict__ A, long long sAz1, int lda,
    const float* __restrict__ B, int ldb,
    float* __restrict__ C, long long sCz1, int ldc,
    const float* __restrict__ bias,
    const float* __restrict__ resid, int ldr,
    float alpha, int M, int N, int K, int act)
{
  constexpr int BK = 16;
  constexpr int TM = BM / 16;
  constexpr int TN = BN / 16;
  __shared__ float As[BK][BM];
  __shared__ float Bs[BK][BN];

  const int z = blockIdx.z;
  A += z * sAz1;
  C += z * sCz1;
  const float* R = resid;

  const int tid = threadIdx.x;
  const int tx = tid & 15, ty = tid >> 4;
  const int m0 = blockIdx.y * BM, n0 = blockIdx.x * BN;

  float acc[TM][TN];
#pragma unroll
  for (int i = 0; i < TM; ++i)
#pragma unroll
    for (int j = 0; j < TN; ++j) acc[i][j] = 0.f;

  for (int k0 = 0; k0 < K; k0 += BK) {
    {
      constexpr int AV = (BM * BK / 4) / 256;
#pragma unroll
      for (int u = 0; u < AV; ++u) {
        const int vi = tid + u * 256;
        const int r  = vi / (BK / 4);
        const int c4 = (vi % (BK / 4)) * 4;
        const int gm = m0 + r, gk = k0 + c4;
        float4 v = {0.f, 0.f, 0.f, 0.f};
        if (gm < M) v = *(const float4*)(A + (long long)gm * lda + gk);
        As[c4 + 0][r] = v.x; As[c4 + 1][r] = v.y;
        As[c4 + 2][r] = v.z; As[c4 + 3][r] = v.w;
      }
    }
    {
      constexpr int BV = (BN * BK / 4) / 256;
#pragma unroll
      for (int u = 0; u < BV; ++u) {
        const int vi = tid + u * 256;
        const int r  = vi / (BK / 4);
        const int c4 = (vi % (BK / 4)) * 4;
        const int gn = n0 + r, gk = k0 + c4;
        float4 v = {0.f, 0.f, 0.f, 0.f};
        if (gn < N) v = *(const float4*)(B + (long long)gn * ldb + gk);
        Bs[c4 + 0][r] = v.x; Bs[c4 + 1][r] = v.y;
        Bs[c4 + 2][r] = v.z; Bs[c4 + 3][r] = v.w;
      }
    }
    __syncthreads();
#pragma unroll
    for (int kk = 0; kk < BK; ++kk) {
      float a[TM], bb[TN];
#pragma unroll
      for (int i = 0; i < TM; i += 4)
        *reinterpret_cast<float4*>(&a[i]) = *reinterpret_cast<const float4*>(&As[kk][ty * TM + i]);
#pragma unroll
      for (int j = 0; j < TN; j += 4)
        *reinterpret_cast<float4*>(&bb[j]) = *reinterpret_cast<const float4*>(&Bs[kk][tx * TN + j]);
#pragma unroll
      for (int i = 0; i < TM; ++i)
#pragma unroll
        for (int j = 0; j < TN; ++j) acc[i][j] = fmaf(a[i], bb[j], acc[i][j]);
    }
    __syncthreads();
  }

#pragma unroll
  for (int i = 0; i < TM; ++i) {
    const int gm = m0 + ty * TM + i;
    if (gm >= M) continue;
#pragma unroll
    for (int j = 0; j < TN; ++j) {
      const int gn = n0 + tx * TN + j;
      if (gn >= N) continue;
      float v = acc[i][j] * alpha;
      if (bias) v += bias[gn];
      if (R)    v += R[(long long)gm * ldr + gn];
      if (act)  v = tanhf(v);
      C[(long long)gm * ldc + gn] = v;
    }
  }
}

// ---------- LayerNorm over whole (SEQ,HID) per sample ----------
__global__ __launch_bounds__(256) void ln_part(const float* __restrict__ x, float* __restrict__ part) {
  const int b = blockIdx.x;            // 0..127
  const int n = b >> 4, seg = b & 15;
  const int per = (SEQL * HIDD / 4) / 16;
  const float4* px = (const float4*)(x + (size_t)n * SEQL * HIDD);
  float s = 0.f, q = 0.f;
  for (int i = seg * per + threadIdx.x; i < (seg + 1) * per; i += 256) {
    float4 v = px[i];
    s += v.x + v.y + v.z + v.w;
    q += v.x * v.x + v.y * v.y + v.z * v.z + v.w * v.w;
  }
  for (int o = 32; o; o >>= 1) { s += __shfl_xor(s, o, 64); q += __shfl_xor(q, o, 64); }
  __shared__ float ls[8];
  const int wid = threadIdx.x >> 6, lane = threadIdx.x & 63;
  if (lane == 0) { ls[wid] = s; ls[4 + wid] = q; }
  __syncthreads();
  if (threadIdx.x == 0) {
    part[b] = ls[0] + ls[1] + ls[2] + ls[3];
    part[128 + b] = ls[4] + ls[5] + ls[6] + ls[7];
  }
}

// LN apply -> bf16; computes per-sample stats from partials in-block (no ln_fin)
__global__ __launch_bounds__(256) void ln_apply_bf(const float* __restrict__ x,
    const float* __restrict__ g, const float* __restrict__ b,
    const float* __restrict__ part, unsigned short* __restrict__ y)
{
  __shared__ float ms[8], rs[8];
  if (threadIdx.x < 8) {
    const int n = threadIdx.x;
    float s = 0.f, qv = 0.f;
    for (int j = 0; j < 16; ++j) { s += part[n * 16 + j]; qv += part[128 + n * 16 + j]; }
    const float inv = 1.f / (float)(SEQL * HIDD);
    const float m = s * inv;
    ms[n] = m;
    rs[n] = rsqrtf(qv * inv - m * m + EPSV);
  }
  __syncthreads();
  const int tot = NBATCH * SEQL * HIDD / 4;
  for (int i = blockIdx.x * 256 + threadIdx.x; i < tot; i += gridDim.x * 256) {
    const int n  = i / (SEQL * HIDD / 4);
    const int se = i - n * (SEQL * HIDD / 4);
    const float m = ms[n], r = rs[n];
    float4 xv = ((const float4*)x)[i];
    float4 gv = ((const float4*)g)[se];
    float4 bv = ((const float4*)b)[se];
    ushort4 o;
    o.x = f2bf((xv.x - m) * r * gv.x + bv.x);
    o.y = f2bf((xv.y - m) * r * gv.y + bv.y);
    o.z = f2bf((xv.z - m) * r * gv.z + bv.z);
    o.w = f2bf((xv.w - m) * r * gv.w + bv.w);
    ((ushort4*)y)[i] = o;
  }
}

// ---------- softmax fp32 (ld 224) -> bf16 (ld 256, zero-padded) ----------
__global__ __launch_bounds__(256) void softmax_bf(const float* __restrict__ S,
                                                  unsigned short* __restrict__ P, int nrows) {
  const int row = blockIdx.x * 4 + (threadIdx.x >> 6);
  const int lane = threadIdx.x & 63;
  if (row >= nrows) return;
  const float* p = S + (long long)row * SLD;
  float v[4];
  float mx = -1e30f;
#pragma unroll
  for (int j = 0; j < 4; ++j) {
    const int t = lane + 64 * j;
    v[j] = (t < SEQL) ? p[t] : -1e30f;
    mx = fmaxf(mx, v[j]);
  }
  for (int o = 32; o; o >>= 1) mx = fmaxf(mx, __shfl_xor(mx, o, 64));
  float sum = 0.f;
#pragma unroll
  for (int j = 0; j < 4; ++j) {
    const int t = lane + 64 * j;
    v[j] = (t < SEQL) ? __expf(v[j] - mx) : 0.f;
    sum += v[j];
  }
  for (int o = 32; o; o >>= 1) sum += __shfl_xor(sum, o, 64);
  const float inv = 1.f / sum;
  unsigned short* q = P + (long long)row * PLD;
#pragma unroll
  for (int j = 0; j < 4; ++j) {
    const int t = lane + 64 * j;
    q[t] = f2bf(v[j] * inv);
  }
}

// ---------- Wo split-K reduce: Ares = sum_s Cpart[s] + bo + Z ----------
__global__ __launch_bounds__(256) void wo_reduce(const float4* __restrict__ Cp,
    const float4* __restrict__ Z4, const float4* __restrict__ bo4,
    float4* __restrict__ out4)
{
  const int tot = M_ALL * HIDD / 4;
  for (int i = blockIdx.x * 256 + threadIdx.x; i < tot; i += gridDim.x * 256) {
    float4 a = Cp[i], b = Cp[tot + i], c = Cp[2 * tot + i], d = Cp[3 * tot + i];
    float4 z = Z4[i];
    float4 bb = bo4[i % (HIDD / 4)];
    float4 o;
    o.x = a.x + b.x + c.x + d.x + z.x + bb.x;
    o.y = a.y + b.y + c.y + d.y + z.y + bb.y;
    o.z = a.z + b.z + c.z + d.z + z.z + bb.z;
    o.w = a.w + b.w + c.w + d.w + z.w + bb.w;
    out4[i] = o;
  }
}

// ---------- CLS row init ----------
__global__ void cls_pos(const float* __restrict__ cls, const float* __restrict__ pos,
                        float* __restrict__ Z) {
  const int n = blockIdx.x;
  for (int e = threadIdx.x; e < HIDD; e += 256)
    Z[(size_t)n * SEQL * HIDD + e] = cls[e] + pos[e];
}

// ---------------------------------------------------------------
extern "C" void kernel_launch(void* const* d_in, const int* in_sizes, int n_in,
                              void* d_out, int out_size, void* d_ws, size_t ws_size,
                              hipStream_t stream)
{
  const float* X    = (const float*)d_in[0];
  const float* Wp   = (const float*)d_in[1];
  const float* bp   = (const float*)d_in[2];
  const float* cls  = (const float*)d_in[3];
  const float* pos  = (const float*)d_in[4];
  const float* ln1g = (const float*)d_in[5];
  const float* ln1b = (const float*)d_in[6];
  const float* Wq   = (const float*)d_in[7];
  const float* bq   = (const float*)d_in[8];
  const float* Wk   = (const float*)d_in[9];
  const float* bk   = (const float*)d_in[10];
  const float* Wv   = (const float*)d_in[11];
  const float* bv   = (const float*)d_in[12];
  const float* Wo   = (const float*)d_in[13];
  const float* bo   = (const float*)d_in[14];
  const float* ln2g = (const float*)d_in[15];
  const float* ln2b = (const float*)d_in[16];
  const float* W2   = (const float*)d_in[17];
  const float* b2   = (const float*)d_in[18];
  const float* Wh   = (const float*)d_in[19];
  const float* bh   = (const float*)d_in[20];
  float* out = (float*)d_out;
  (void)in_sizes; (void)n_in; (void)out_size; (void)ws_size;

  // NOTE: allocation ORDER matters — gemm_bt edge tiles read up to ~5 MB past
  // QKVb/Xnb ends; the weight copies placed after them keep those reads mapped.
  char* base = (char*)d_ws;
  size_t off = 0;
  auto alloc = [&](size_t bytes) -> char* {
    char* r = base + off;
    off += (bytes + 255) & ~(size_t)255;
    return r;
  };
  const size_t ZB   = (size_t)M_ALL * HIDD * 4;
  const size_t XB   = (size_t)M_ALL * HIDD * 2;
  const size_t SFB  = (size_t)NBATCH * NHEADS * SEQL * SLD * 4;
  const size_t PB   = (size_t)NBATCH * NHEADS * SEQL * PLD * 2;
  const size_t QKVB = (size_t)M_ALL * HH3 * 2;               // 87.15 MB
  const size_t WQB  = (size_t)HH3 * HIDD * 2;                // 42.47 MB
  const size_t WOB  = (size_t)HH * HIDD * 2;                 // 14.16 MB
  const size_t W2B  = (size_t)HIDD * HIDD * 2;

  float*          Z     = (float*)alloc(ZB);
  float*          Ares  = (float*)alloc(ZB);
  unsigned short* Xnb   = (unsigned short*)alloc(XB);
  float*          stats = (float*)alloc(4096);
  float*          Sf    = (float*)alloc(SFB);
  unsigned short* Pb    = (unsigned short*)alloc(PB);
  unsigned short* QKVb  = (unsigned short*)alloc(QKVB);   // Q|K|V slices; H overwrites Q
  unsigned short* Wqkv_bf = (unsigned short*)alloc(WQB);
  unsigned short* Wo_bf   = (unsigned short*)alloc(WOB);
  unsigned short* W2_bf   = (unsigned short*)alloc(W2B);
  float*          bqkv    = (float*)alloc(HH3 * 4);
  float*          Cpart   = (float*)Sf;   // Wo split-K partials alias Sf (+Pb tail)

  const float scale = 1.0f / ((float)HIDD * (float)HIDD);
  const long long sTn = (long long)SEQL * HH3;
  const long long sSn = (long long)NHEADS * SEQL * SLD;
  const long long sSh = (long long)SEQL * SLD;
  const long long sPn = (long long)NHEADS * SEQL * PLD;
  const long long sPh = (long long)SEQL * PLD;
  const int WO4 = HH * HIDD / 4, W24 = HIDD * HIDD / 4;

  // ---- one-time weight conversion ----
  cvt_bf<<<dim3(4096), 256, 0, stream>>>((const float4*)Wq, (ushort4*)(Wqkv_bf), WO4);
  cvt_bf<<<dim3(4096), 256, 0, stream>>>((const float4*)Wk, (ushort4*)(Wqkv_bf + (size_t)HH * HIDD), WO4);
  cvt_bf<<<dim3(4096), 256, 0, stream>>>((const float4*)Wv, (ushort4*)(Wqkv_bf + (size_t)2 * HH * HIDD), WO4);
  cvt_bf<<<dim3(4096), 256, 0, stream>>>((const float4*)Wo, (ushort4*)Wo_bf, WO4);
  cvt_bf<<<dim3(512),  256, 0, stream>>>((const float4*)W2, (ushort4*)W2_bf, W24);
  hipMemcpyAsync(bqkv,          bq, (size_t)HH * 4, hipMemcpyDeviceToDevice, stream);
  hipMemcpyAsync(bqkv + HH,     bk, (size_t)HH * 4, hipMemcpyDeviceToDevice, stream);
  hipMemcpyAsync(bqkv + 2 * HH, bv, (size_t)HH * 4, hipMemcpyDeviceToDevice, stream);

  // ---- embed ----
  cls_pos<<<dim3(NBATCH), 256, 0, stream>>>(cls, pos, Z);
  gemm_k<64, 64><<<dim3(HIDD / 64, (NPATCH + 63) / 64, NBATCH), 256, 0, stream>>>(
      X, (long long)NPATCH * PATCHD, PATCHD,
      Wp, PATCHD,
      Z + HIDD, (long long)SEQL * HIDD, HIDD,
      bp, pos + HIDD, HIDD,
      1.0f, NPATCH, HIDD, PATCHD, 0);

  for (int blk = 0; blk < NBLOCKS; ++blk) {
    // ---- LN1 -> Xnb (bf16) ----
    ln_part<<<dim3(128), 256, 0, stream>>>(Z, stats);
    ln_apply_bf<<<dim3(1182), 256, 0, stream>>>(Z, ln1g, ln1b, stats, Xnb);

    // ---- fused QKV: [1576,768] @ [27648,768]^T -> bf16 [1576,27648] ----
    gemm_bt<128, 128, 2, 2, true><<<dim3((HH3 / 128) * 13, 1, 1), 256, 0, stream>>>(
        Xnb, 0, 0, HIDD, Wqkv_bf, 0, 0, HIDD, QKVb, 0, 0, HH3,
        bqkv, 1, 1.0f, M_ALL, HH3, HIDD, 13);

    // ---- scores: Sf[z] = scale * Q[z] @ K[z]^T  (z = n*12+h) ----
    gemm_bt<64, 64, 2, 2, false><<<dim3(16, 1, NBATCH * NHEADS), 256, 0, stream>>>(
        QKVb, sTn, HIDD, HH3,
        QKVb + HH, sTn, HIDD, HH3,
        Sf, sSn, sSh, SLD,
        nullptr, NHEADS, scale, SEQL, SEQL, HIDD, 4);

    // ---- softmax rows -> Pb ----
    softmax_bf<<<dim3(NBATCH * NHEADS * SEQL / 4), 256, 0, stream>>>(
        Sf, Pb, NBATCH * NHEADS * SEQL);

    // ---- PV: H[z] = P[z] @ V[z]; H into the dead Q column slice ----
    gemm_nn<64, 128, true><<<dim3(HIDD / 128, 4, NBATCH * NHEADS), 256, 0, stream>>>(
        Pb, sPn, sPh, PLD,
        QKVb + 2 * HH, sTn, HIDD, HH3,
        QKVb, sTn, HIDD, HH3,
        nullptr, NHEADS, 1.0f, SEQL, HIDD, KPV, SEQL);

    // ---- Wo split-K: Cpart[s] = H[:, s*2304:(s+1)*2304] @ Wo_s^T ----
    // BN=64 -> 624 blocks (2.4/CU) fixes the 312-block CU starvation of R7.
    gemm_bt<128, 64, 2, 2, false><<<dim3((HIDD / 64) * 13, 1, KSPLIT), 256, 0, stream>>>(
        QKVb, 0, HH / KSPLIT, HH3,
        Wo_bf, 0, HH / KSPLIT, HH,
        Cpart, 0, (long long)M_ALL * HIDD, HIDD,
        nullptr, KSPLIT, 1.0f, M_ALL, HIDD, HH / KSPLIT, 13);

    // ---- reduce + bias + residual -> Ares ----
    wo_reduce<<<dim3(1182), 256, 0, stream>>>(
        (const float4*)Cpart, (const float4*)Z, (const float4*)bo, (float4*)Ares);

    // ---- LN2 -> Xnb (bf16) ----
    ln_part<<<dim3(128), 256, 0, stream>>>(Ares, stats);
    ln_apply_bf<<<dim3(1182), 256, 0, stream>>>(Ares, ln2g, ln2b, stats, Xnb);

    // ---- W2: Z = Xnb @ W2^T + b2 (fp32 out) ----
    gemm_bt<128, 64, 2, 2, false><<<dim3((HIDD / 64) * 13, 1, 1), 256, 0, stream>>>(
        Xnb, 0, 0, HIDD, W2_bf, 0, 0, HIDD, Z, 0, 0, HIDD,
        b2, 1, 1.0f, M_ALL, HIDD, HIDD, 13);
  }

  // ---- head: out = tanh(Z[:,0,:] @ Wh^T + bh) ----
  gemm_k<64, 64><<<dim3((OUTDIM + 63) / 64, 1, 1), 256, 0, stream>>>(
      Z, 0, SEQL * HIDD,
      Wh, HIDD,
      out, 0, OUTDIM,
      bh, nullptr, 0,
      1.0f, NBATCH, OUTDIM, HIDD, 1);
}